// Round 1
// baseline (265.119 us; speedup 1.0000x reference)
//
#include <hip/hip_runtime.h>
#include <stdint.h>
#include <stddef.h>

// MHA forward, MI355X gfx950. B=2 S=2048 D=1024 H=16 hd=64.
// bf16 MFMA (16x16x32) everywhere, fp32 accum, fp32 output.

typedef __bf16 bf16_t;
typedef __bf16 bf16x8 __attribute__((ext_vector_type(8)));
typedef __bf16 bf16x4 __attribute__((ext_vector_type(4)));
typedef float  f32x4  __attribute__((ext_vector_type(4)));

static constexpr float kQScale = 0.18033688011112042f; // (1/sqrt(64)) * log2(e); softmax done in base-2

__device__ __forceinline__ void gload_lds16(const bf16_t* g, bf16_t* l) {
  __builtin_amdgcn_global_load_lds((__attribute__((address_space(1))) void*)(void*)g,
                                   (__attribute__((address_space(3))) void*)l, 16, 0, 0);
}

// ---------------- K1: cast x (f32) -> xb (bf16) ----------------
__global__ __launch_bounds__(256) void cast_x_k(const float* __restrict__ x, bf16_t* __restrict__ xb) {
  int i = blockIdx.x * 256 + threadIdx.x;      // 1M threads, 4 elems each
  float4 v = ((const float4*)x)[i];
  bf16x4 o;
  o[0] = (bf16_t)v.x; o[1] = (bf16_t)v.y; o[2] = (bf16_t)v.z; o[3] = (bf16_t)v.w;
  ((bf16x4*)xb)[i] = o;
}

// ---------------- K2: transpose+cast weights: wT[n][k] = w[k][n] ----------------
__global__ __launch_bounds__(256) void transpose_w_k(
    const float* __restrict__ wq, const float* __restrict__ wk,
    const float* __restrict__ wv, const float* __restrict__ wo,
    bf16_t* __restrict__ wqkvT, bf16_t* __restrict__ woT) {
  __shared__ float t[64][65];
  int z = blockIdx.z;
  const float* src = z == 0 ? wq : z == 1 ? wk : z == 2 ? wv : wo;
  bf16_t* dst = z < 3 ? wqkvT + (size_t)z * 1024 * 1024 : woT;
  int n0 = blockIdx.x * 64, k0 = blockIdx.y * 64;
  int c = threadIdx.x & 63, r4 = threadIdx.x >> 6;
#pragma unroll
  for (int i = 0; i < 16; ++i) {
    int r = r4 + i * 4;
    t[r][c] = src[(size_t)(k0 + r) * 1024 + (n0 + c)];
  }
  __syncthreads();
#pragma unroll
  for (int i = 0; i < 16; ++i) {
    int r = r4 + i * 4;
    dst[(size_t)(n0 + r) * 1024 + (k0 + c)] = (bf16_t)t[c][r];
  }
}

// ---------------- K3/K6: bf16 GEMM, m97 structure (128x128 tile, BK=32) ----------------
// A: [M][1024] bf16 row-major.  Bw: [N][1024] bf16 (row n = output col, contiguous k).
// EPI 0: epilogue -> Q/K/V [b][h][s][64] bf16 (+bias, Q scaled).  EPI 1: f32 out + bias.
template <int EPI>
__global__ __launch_bounds__(256) void gemm_k(
    const bf16_t* __restrict__ A, const bf16_t* __restrict__ Bw,
    bf16_t* __restrict__ Qb, bf16_t* __restrict__ Kb, bf16_t* __restrict__ Vb,
    const float* __restrict__ bq, const float* __restrict__ bk, const float* __restrict__ bv,
    float* __restrict__ outF, const float* __restrict__ bo) {
  __shared__ alignas(16) bf16_t As[128 * 32];
  __shared__ alignas(16) bf16_t Bs[128 * 32];
  const int tid = threadIdx.x;
  const int lane = tid & 63;
  const int w = tid >> 6, wr = w >> 1, wc = w & 1;
  const int brow = blockIdx.y * 128, bcol = blockIdx.x * 128;
  const int l15 = lane & 15, ko = (lane >> 4) * 8;

  f32x4 acc[4][4] = {};
  const bf16_t* Ab = A + (size_t)brow * 1024;
  const bf16_t* Bb = Bw + (size_t)bcol * 1024;

  const int e0 = tid * 8;            // LDS elem offset, issue 0 (linear per-lane order)
  const int r0 = e0 >> 5, c0 = e0 & 31;

  for (int k0 = 0; k0 < 1024; k0 += 32) {
    gload_lds16(Ab + (size_t)r0 * 1024 + k0 + c0, &As[e0]);
    gload_lds16(Ab + (size_t)(r0 + 64) * 1024 + k0 + c0, &As[e0 + 2048]);
    gload_lds16(Bb + (size_t)r0 * 1024 + k0 + c0, &Bs[e0]);
    gload_lds16(Bb + (size_t)(r0 + 64) * 1024 + k0 + c0, &Bs[e0 + 2048]);
    __syncthreads();
    bf16x8 af[4], bfg[4];
#pragma unroll
    for (int i = 0; i < 4; ++i)
      af[i] = *(const bf16x8*)&As[(wr * 64 + i * 16 + l15) * 32 + ko];
#pragma unroll
    for (int i = 0; i < 4; ++i)
      bfg[i] = *(const bf16x8*)&Bs[(wc * 64 + i * 16 + l15) * 32 + ko];
#pragma unroll
    for (int i = 0; i < 4; ++i)
#pragma unroll
      for (int j = 0; j < 4; ++j)
        acc[i][j] = __builtin_amdgcn_mfma_f32_16x16x32_bf16(af[i], bfg[j], acc[i][j], 0, 0, 0);
    __syncthreads();
  }

#pragma unroll
  for (int i = 0; i < 4; ++i) {
    const int gm0 = brow + wr * 64 + i * 16 + ((lane >> 4) << 2);
#pragma unroll
    for (int j = 0; j < 4; ++j) {
      const int gn = bcol + wc * 64 + j * 16 + l15;
      if constexpr (EPI == 0) {
        const int mat = gn >> 10;          // uniform per block (bcol%1024+127 < 1024)
        const int col = gn & 1023;
        bf16_t* dst = mat == 0 ? Qb : (mat == 1 ? Kb : Vb);
        const float* bias = mat == 0 ? bq : (mat == 1 ? bk : bv);
        const float scl = mat == 0 ? kQScale : 1.0f;
        const float bsv = bias[col];
        const int h = col >> 6, dd = col & 63;
#pragma unroll
        for (int r = 0; r < 4; ++r) {
          const int m = gm0 + r;
          const int b = m >> 11, s = m & 2047;
          dst[((((size_t)b * 16 + h) * 2048 + s) * 64 + dd)] = (bf16_t)((acc[i][j][r] + bsv) * scl);
        }
      } else {
        const float bsv = bo[gn];
#pragma unroll
        for (int r = 0; r < 4; ++r)
          outF[(size_t)(gm0 + r) * 1024 + gn] = acc[i][j][r] + bsv;
      }
    }
  }
}

// ---------------- K4: transpose V [bh][s][64] -> Vt [bh][64][s] ----------------
__global__ __launch_bounds__(256) void transpose_v_k(const bf16_t* __restrict__ V, bf16_t* __restrict__ Vt) {
  __shared__ bf16_t t[64][65];
  int bh = blockIdx.y, s0 = blockIdx.x * 64;
  const bf16_t* src = V + (size_t)bh * 2048 * 64;
  bf16_t* dst = Vt + (size_t)bh * 64 * 2048;
  int c = threadIdx.x & 63, r4 = threadIdx.x >> 6;
#pragma unroll
  for (int i = 0; i < 16; ++i) {
    int r = r4 + i * 4;
    t[r][c] = src[(size_t)(s0 + r) * 64 + c];
  }
  __syncthreads();
#pragma unroll
  for (int i = 0; i < 16; ++i) {
    int d = r4 + i * 4;
    dst[(size_t)d * 2048 + s0 + c] = t[c][d];
  }
}

// ---------------- K5: flash attention ----------------
// Q [bh][s][64] (pre-scaled by log2e/8), K [bh][s][64], Vt [bh][64][s], all bf16.
// Block: 4 independent waves; wave owns 32 q-rows. KV tile = 64. Online softmax base-2.
__global__ __launch_bounds__(256) void attn_k(
    const bf16_t* __restrict__ Qb, const bf16_t* __restrict__ Kb,
    const bf16_t* __restrict__ Vt, bf16_t* __restrict__ O) {
  __shared__ alignas(16) bf16_t P_lds[4][32][72];   // pad 64->72 (144B rows: 2-way banks, 16B aligned)
  const int tid = threadIdx.x, lane = tid & 63, w = tid >> 6;
  const int bh = blockIdx.y;
  const int q0 = blockIdx.x * 128 + w * 32;
  const int l15 = lane & 15, lhi = lane >> 4;

  const bf16_t* Qp = Qb + ((size_t)bh * 2048 + q0) * 64;
  const bf16_t* Kp = Kb + (size_t)bh * 2048 * 64;
  const bf16_t* Vp = Vt + (size_t)bh * 64 * 2048;

  bf16x8 qa[2][2];
#pragma unroll
  for (int m = 0; m < 2; ++m)
#pragma unroll
    for (int kk = 0; kk < 2; ++kk)
      qa[m][kk] = *(const bf16x8*)&Qp[(size_t)(m * 16 + l15) * 64 + kk * 32 + lhi * 8];

  f32x4 o[2][4] = {};
  float mx[2][4], li[2][4];
#pragma unroll
  for (int m = 0; m < 2; ++m)
#pragma unroll
    for (int r = 0; r < 4; ++r) { mx[m][r] = -1e30f; li[m][r] = 0.0f; }

  for (int kv0 = 0; kv0 < 2048; kv0 += 64) {
    // S = Q K^T (already log2e/8-scaled via Q)
    f32x4 s[2][4] = {};
#pragma unroll
    for (int fn = 0; fn < 4; ++fn) {
      bf16x8 kf0 = *(const bf16x8*)&Kp[(size_t)(kv0 + fn * 16 + l15) * 64 + 0 + lhi * 8];
      bf16x8 kf1 = *(const bf16x8*)&Kp[(size_t)(kv0 + fn * 16 + l15) * 64 + 32 + lhi * 8];
#pragma unroll
      for (int m = 0; m < 2; ++m) {
        s[m][fn] = __builtin_amdgcn_mfma_f32_16x16x32_bf16(qa[m][0], kf0, s[m][fn], 0, 0, 0);
        s[m][fn] = __builtin_amdgcn_mfma_f32_16x16x32_bf16(qa[m][1], kf1, s[m][fn], 0, 0, 0);
      }
    }
    // online softmax (rows: lhi*4+r; cols: l15 across the 16-lane group + fn)
#pragma unroll
    for (int m = 0; m < 2; ++m) {
#pragma unroll
      for (int r = 0; r < 4; ++r) {
        float t0 = fmaxf(fmaxf(s[m][0][r], s[m][1][r]), fmaxf(s[m][2][r], s[m][3][r]));
        t0 = fmaxf(t0, __shfl_xor(t0, 1));
        t0 = fmaxf(t0, __shfl_xor(t0, 2));
        t0 = fmaxf(t0, __shfl_xor(t0, 4));
        t0 = fmaxf(t0, __shfl_xor(t0, 8));
        const float mn = fmaxf(mx[m][r], t0);
        const float corr = exp2f(mx[m][r] - mn);
        mx[m][r] = mn;
        float rs = 0.0f;
#pragma unroll
        for (int fn = 0; fn < 4; ++fn) {
          const float p = exp2f(s[m][fn][r] - mn);
          s[m][fn][r] = p;
          rs += p;
        }
        rs += __shfl_xor(rs, 1);
        rs += __shfl_xor(rs, 2);
        rs += __shfl_xor(rs, 4);
        rs += __shfl_xor(rs, 8);
        li[m][r] = li[m][r] * corr + rs;
#pragma unroll
        for (int fd = 0; fd < 4; ++fd) o[m][fd][r] *= corr;
      }
#pragma unroll
      for (int fn = 0; fn < 4; ++fn)
#pragma unroll
        for (int r = 0; r < 4; ++r)
          P_lds[w][m * 16 + lhi * 4 + r][fn * 16 + l15] = (bf16_t)s[m][fn][r];
    }
    __builtin_amdgcn_wave_barrier();
    // O += P V  (Vt gives contiguous-k B fragments)
    bf16x8 vf[4][2];
#pragma unroll
    for (int fd = 0; fd < 4; ++fd)
#pragma unroll
      for (int kk = 0; kk < 2; ++kk)
        vf[fd][kk] = *(const bf16x8*)&Vp[(size_t)(fd * 16 + l15) * 2048 + kv0 + kk * 32 + lhi * 8];
#pragma unroll
    for (int m = 0; m < 2; ++m) {
#pragma unroll
      for (int kk = 0; kk < 2; ++kk) {
        bf16x8 pa = *(const bf16x8*)&P_lds[w][m * 16 + l15][kk * 32 + lhi * 8];
#pragma unroll
        for (int fd = 0; fd < 4; ++fd)
          o[m][fd] = __builtin_amdgcn_mfma_f32_16x16x32_bf16(pa, vf[fd][kk], o[m][fd], 0, 0, 0);
      }
    }
  }

  const int b = bh >> 4, h = bh & 15;
#pragma unroll
  for (int m = 0; m < 2; ++m)
#pragma unroll
    for (int r = 0; r < 4; ++r) {
      const float inv = 1.0f / li[m][r];
      const int row = b * 2048 + q0 + m * 16 + lhi * 4 + r;
#pragma unroll
      for (int fd = 0; fd < 4; ++fd) {
        const int col = h * 64 + fd * 16 + l15;
        O[(size_t)row * 1024 + col] = (bf16_t)(o[m][fd][r] * inv);
      }
    }
}

// ---------------- launch ----------------
extern "C" void kernel_launch(void* const* d_in, const int* in_sizes, int n_in,
                              void* d_out, int out_size, void* d_ws, size_t ws_size,
                              hipStream_t stream) {
  const float* x  = (const float*)d_in[0];
  const float* wq = (const float*)d_in[1];
  const float* bq = (const float*)d_in[2];
  const float* wk = (const float*)d_in[3];
  const float* bk = (const float*)d_in[4];
  const float* wv = (const float*)d_in[5];
  const float* bv = (const float*)d_in[6];
  const float* wo = (const float*)d_in[7];
  const float* bo = (const float*)d_in[8];
  float* out = (float*)d_out;

  if (ws_size < ((size_t)48 << 20)) return;  // need 48MB scratch
  char* ws = (char*)d_ws;
  bf16_t* xb  = (bf16_t*)(ws);                    // 8MB x bf16 [4096][1024]; reused as O after proj
  bf16_t* wT  = (bf16_t*)(ws + ((size_t)8 << 20)); // 6MB wqkvT [3072][1024] + 2MB woT
  bf16_t* woT = wT + (size_t)3072 * 1024;
  bf16_t* Qb  = (bf16_t*)(ws + ((size_t)16 << 20)); // [2][16][2048][64] bf16
  bf16_t* Kb  = (bf16_t*)(ws + ((size_t)24 << 20));
  bf16_t* Vb  = (bf16_t*)(ws + ((size_t)32 << 20));
  bf16_t* Vt  = (bf16_t*)(ws + ((size_t)40 << 20)); // [2][16][64][2048]
  bf16_t* O   = xb;

  cast_x_k<<<4096, 256, 0, stream>>>(x, xb);
  transpose_w_k<<<dim3(16, 16, 4), 256, 0, stream>>>(wq, wk, wv, wo, wT, woT);
  gemm_k<0><<<dim3(24, 32), 256, 0, stream>>>(xb, wT, Qb, Kb, Vb, bq, bk, bv, nullptr, nullptr);
  transpose_v_k<<<dim3(32, 32), 256, 0, stream>>>(Vb, Vt);
  attn_k<<<dim3(16, 32), 256, 0, stream>>>(Qb, Kb, Vt, O);
  gemm_k<1><<<dim3(8, 32), 256, 0, stream>>>(O, woT, nullptr, nullptr, nullptr,
                                             nullptr, nullptr, nullptr, out, bo);
}

// Round 2
// 197.949 us; speedup vs baseline: 1.3393x; 1.3393x over previous
//
#include <hip/hip_runtime.h>
#include <stdint.h>
#include <stddef.h>

// MHA forward, MI355X gfx950. B=2 S=2048 D=1024 H=16 hd=64.
// bf16 MFMA (16x16x32) everywhere, fp32 accum, fp32 output.

typedef __bf16 bf16_t;
typedef __bf16 bf16x8 __attribute__((ext_vector_type(8)));
typedef __bf16 bf16x4 __attribute__((ext_vector_type(4)));
typedef float  f32x4  __attribute__((ext_vector_type(4)));

static constexpr float kQScale = 0.18033688011112042f; // (1/sqrt(64)) * log2(e); softmax done in base-2

__device__ __forceinline__ void gload_lds16(const bf16_t* g, bf16_t* l) {
  __builtin_amdgcn_global_load_lds((__attribute__((address_space(1))) void*)(void*)g,
                                   (__attribute__((address_space(3))) void*)l, 16, 0, 0);
}

// ---------------- K1: cast x (f32) -> xb (bf16) ----------------
__global__ __launch_bounds__(256) void cast_x_k(const float* __restrict__ x, bf16_t* __restrict__ xb) {
  int i = blockIdx.x * 256 + threadIdx.x;      // 1M threads, 4 elems each
  float4 v = ((const float4*)x)[i];
  bf16x4 o;
  o[0] = (bf16_t)v.x; o[1] = (bf16_t)v.y; o[2] = (bf16_t)v.z; o[3] = (bf16_t)v.w;
  ((bf16x4*)xb)[i] = o;
}

// ---------------- K2: transpose+cast weights: wT[n][k] = w[k][n] ----------------
__global__ __launch_bounds__(256) void transpose_w_k(
    const float* __restrict__ wq, const float* __restrict__ wk,
    const float* __restrict__ wv, const float* __restrict__ wo,
    bf16_t* __restrict__ wqkvT, bf16_t* __restrict__ woT) {
  __shared__ float t[64][65];
  int z = blockIdx.z;
  const float* src = z == 0 ? wq : z == 1 ? wk : z == 2 ? wv : wo;
  bf16_t* dst = z < 3 ? wqkvT + (size_t)z * 1024 * 1024 : woT;
  int n0 = blockIdx.x * 64, k0 = blockIdx.y * 64;
  int c = threadIdx.x & 63, r4 = threadIdx.x >> 6;
#pragma unroll
  for (int i = 0; i < 16; ++i) {
    int r = r4 + i * 4;
    t[r][c] = src[(size_t)(k0 + r) * 1024 + (n0 + c)];
  }
  __syncthreads();
#pragma unroll
  for (int i = 0; i < 16; ++i) {
    int r = r4 + i * 4;
    dst[(size_t)(n0 + r) * 1024 + (k0 + c)] = (bf16_t)t[c][r];
  }
}

// ---------------- K3/K6: bf16 GEMM, m97 structure (128x128 tile, BK=32) ----------------
// A: [M][1024] bf16 row-major.  Bw: [N][1024] bf16 (row n = output col, contiguous k).
// EPI 0: epilogue -> Q/K/V [b][h][s][64] bf16 (+bias, Q scaled).  EPI 1: f32 out + bias.
template <int EPI>
__global__ __launch_bounds__(256) void gemm_k(
    const bf16_t* __restrict__ A, const bf16_t* __restrict__ Bw,
    bf16_t* __restrict__ Qb, bf16_t* __restrict__ Kb, bf16_t* __restrict__ Vb,
    const float* __restrict__ bq, const float* __restrict__ bk, const float* __restrict__ bv,
    float* __restrict__ outF, const float* __restrict__ bo) {
  __shared__ alignas(16) bf16_t As[128 * 32];
  __shared__ alignas(16) bf16_t Bs[128 * 32];
  const int tid = threadIdx.x;
  const int lane = tid & 63;
  const int w = tid >> 6, wr = w >> 1, wc = w & 1;
  const int brow = blockIdx.y * 128, bcol = blockIdx.x * 128;
  const int l15 = lane & 15, ko = (lane >> 4) * 8;

  f32x4 acc[4][4] = {};
  const bf16_t* Ab = A + (size_t)brow * 1024;
  const bf16_t* Bb = Bw + (size_t)bcol * 1024;

  const int e0 = tid * 8;            // LDS elem offset, issue 0 (linear per-lane order)
  const int r0 = e0 >> 5, c0 = e0 & 31;

  for (int k0 = 0; k0 < 1024; k0 += 32) {
    gload_lds16(Ab + (size_t)r0 * 1024 + k0 + c0, &As[e0]);
    gload_lds16(Ab + (size_t)(r0 + 64) * 1024 + k0 + c0, &As[e0 + 2048]);
    gload_lds16(Bb + (size_t)r0 * 1024 + k0 + c0, &Bs[e0]);
    gload_lds16(Bb + (size_t)(r0 + 64) * 1024 + k0 + c0, &Bs[e0 + 2048]);
    __syncthreads();
    bf16x8 af[4], bfg[4];
#pragma unroll
    for (int i = 0; i < 4; ++i)
      af[i] = *(const bf16x8*)&As[(wr * 64 + i * 16 + l15) * 32 + ko];
#pragma unroll
    for (int i = 0; i < 4; ++i)
      bfg[i] = *(const bf16x8*)&Bs[(wc * 64 + i * 16 + l15) * 32 + ko];
#pragma unroll
    for (int i = 0; i < 4; ++i)
#pragma unroll
      for (int j = 0; j < 4; ++j)
        acc[i][j] = __builtin_amdgcn_mfma_f32_16x16x32_bf16(af[i], bfg[j], acc[i][j], 0, 0, 0);
    __syncthreads();
  }

#pragma unroll
  for (int i = 0; i < 4; ++i) {
    const int gm0 = brow + wr * 64 + i * 16 + ((lane >> 4) << 2);
#pragma unroll
    for (int j = 0; j < 4; ++j) {
      const int gn = bcol + wc * 64 + j * 16 + l15;
      if constexpr (EPI == 0) {
        const int mat = gn >> 10;          // uniform per block (bcol%1024+127 < 1024)
        const int col = gn & 1023;
        bf16_t* dst = mat == 0 ? Qb : (mat == 1 ? Kb : Vb);
        const float* bias = mat == 0 ? bq : (mat == 1 ? bk : bv);
        const float scl = mat == 0 ? kQScale : 1.0f;
        const float bsv = bias[col];
        const int h = col >> 6, dd = col & 63;
#pragma unroll
        for (int r = 0; r < 4; ++r) {
          const int m = gm0 + r;
          const int b = m >> 11, s = m & 2047;
          dst[((((size_t)b * 16 + h) * 2048 + s) * 64 + dd)] = (bf16_t)((acc[i][j][r] + bsv) * scl);
        }
      } else {
        const float bsv = bo[gn];
#pragma unroll
        for (int r = 0; r < 4; ++r)
          outF[(size_t)(gm0 + r) * 1024 + gn] = acc[i][j][r] + bsv;
      }
    }
  }
}

// ---------------- K4: transpose V [bh][s][64] -> Vt [bh][64][s] ----------------
__global__ __launch_bounds__(256) void transpose_v_k(const bf16_t* __restrict__ V, bf16_t* __restrict__ Vt) {
  __shared__ bf16_t t[64][65];
  int bh = blockIdx.y, s0 = blockIdx.x * 64;
  const bf16_t* src = V + (size_t)bh * 2048 * 64;
  bf16_t* dst = Vt + (size_t)bh * 64 * 2048;
  int c = threadIdx.x & 63, r4 = threadIdx.x >> 6;
#pragma unroll
  for (int i = 0; i < 16; ++i) {
    int r = r4 + i * 4;
    t[r][c] = src[(size_t)(s0 + r) * 64 + c];
  }
  __syncthreads();
#pragma unroll
  for (int i = 0; i < 16; ++i) {
    int d = r4 + i * 4;
    dst[(size_t)d * 2048 + s0 + c] = t[c][d];
  }
}

// ---------------- K5: flash attention (swapped-QK^T, in-register softmax) ----------------
// Q [bh][s][64] (pre-scaled by log2e/8), K [bh][s][64], Vt [bh][64][s], all bf16.
// 4 independent waves/block; wave owns 32 q-rows (2 m-tiles of 16). KV tile = 64.
// S^T = mfma(K,Q): lane (l15,lhi) holds q=l15, k = lhi*4+r+16*fn -> in-lane softmax,
// only 2 shuffles (xor16/xor32) per reduce. P^T packs as contiguous-k bf16x4 ->
// vectorized LDS roundtrip. O^T = mfma(V^T, P^T): col=q, row=d.
__global__ __launch_bounds__(256, 2) void attn_k(
    const bf16_t* __restrict__ Qb, const bf16_t* __restrict__ Kb,
    const bf16_t* __restrict__ Vt, bf16_t* __restrict__ O) {
  __shared__ alignas(16) bf16_t P_lds[4][2][16][72];   // [wave][m][q][k+pad]; 144B row stride
  const int tid = threadIdx.x, lane = tid & 63, w = tid >> 6;
  const int l15 = lane & 15, lhi = lane >> 4;
  // bijective XCD-chunked swizzle: 512 blocks, 64 consecutive per XCD -> 4 heads/XCD L2
  const int work = (blockIdx.x & 7) * 64 + (blockIdx.x >> 3);
  const int bh = work >> 4;
  const int q0 = (work & 15) * 128 + w * 32;

  const bf16_t* Qp = Qb + ((size_t)bh * 2048 + q0) * 64;
  const bf16_t* Kp = Kb + (size_t)bh * 2048 * 64;
  const bf16_t* Vp = Vt + (size_t)bh * 64 * 2048;

  bf16x8 qa[2][2];   // B-operand: [q=l15][k=kk*32+lhi*8+..]
#pragma unroll
  for (int m = 0; m < 2; ++m)
#pragma unroll
    for (int kk = 0; kk < 2; ++kk)
      qa[m][kk] = *(const bf16x8*)&Qp[(size_t)(m * 16 + l15) * 64 + kk * 32 + lhi * 8];

  f32x4 o[2][4] = {};
  float mx[2] = {-1e30f, -1e30f}, li[2] = {0.0f, 0.0f};

  bf16x8 kc[4][2], kn[4][2], vf[4][2];
#pragma unroll
  for (int fn = 0; fn < 4; ++fn)
#pragma unroll
    for (int kk = 0; kk < 2; ++kk)
      kc[fn][kk] = *(const bf16x8*)&Kp[(size_t)(fn * 16 + l15) * 64 + kk * 32 + lhi * 8];

  for (int kv0 = 0; kv0 < 2048; kv0 += 64) {
    const int nxt = (kv0 + 64 < 2048) ? kv0 + 64 : 0;   // wrap keeps addr valid; data unused on last iter
    // prefetch V(t) (used after softmax) and K(t+1) (used next iter)
#pragma unroll
    for (int fd = 0; fd < 4; ++fd)
#pragma unroll
      for (int kk = 0; kk < 2; ++kk)
        vf[fd][kk] = *(const bf16x8*)&Vp[(size_t)(fd * 16 + l15) * 2048 + kv0 + kk * 32 + lhi * 8];
#pragma unroll
    for (int fn = 0; fn < 4; ++fn)
#pragma unroll
      for (int kk = 0; kk < 2; ++kk)
        kn[fn][kk] = *(const bf16x8*)&Kp[(size_t)(nxt + fn * 16 + l15) * 64 + kk * 32 + lhi * 8];

    // S^T = K Q^T  (Q pre-scaled by log2e/8)
    f32x4 s[2][4] = {};
    __builtin_amdgcn_s_setprio(1);
#pragma unroll
    for (int fn = 0; fn < 4; ++fn)
#pragma unroll
      for (int m = 0; m < 2; ++m) {
        s[m][fn] = __builtin_amdgcn_mfma_f32_16x16x32_bf16(kc[fn][0], qa[m][0], s[m][fn], 0, 0, 0);
        s[m][fn] = __builtin_amdgcn_mfma_f32_16x16x32_bf16(kc[fn][1], qa[m][1], s[m][fn], 0, 0, 0);
      }
    __builtin_amdgcn_s_setprio(0);

    // online softmax: each lane owns q=l15's 16 k-values; reduce in-lane + xor16/xor32
#pragma unroll
    for (int m = 0; m < 2; ++m) {
      float t0 = fmaxf(fmaxf(s[m][0][0], s[m][0][1]), fmaxf(s[m][0][2], s[m][0][3]));
      float t1 = fmaxf(fmaxf(s[m][1][0], s[m][1][1]), fmaxf(s[m][1][2], s[m][1][3]));
      float t2 = fmaxf(fmaxf(s[m][2][0], s[m][2][1]), fmaxf(s[m][2][2], s[m][2][3]));
      float t3 = fmaxf(fmaxf(s[m][3][0], s[m][3][1]), fmaxf(s[m][3][2], s[m][3][3]));
      float t = fmaxf(fmaxf(t0, t1), fmaxf(t2, t3));
      t = fmaxf(t, __shfl_xor(t, 16));
      t = fmaxf(t, __shfl_xor(t, 32));
      const float mn = fmaxf(mx[m], t);
      const float corr = exp2f(mx[m] - mn);
      mx[m] = mn;
      float rs = 0.0f;
#pragma unroll
      for (int fn = 0; fn < 4; ++fn) {
#pragma unroll
        for (int r = 0; r < 4; ++r) {
          const float p = exp2f(s[m][fn][r] - mn);
          s[m][fn][r] = p;
          rs += p;
        }
      }
      rs += __shfl_xor(rs, 16);
      rs += __shfl_xor(rs, 32);
      li[m] = li[m] * corr + rs;
#pragma unroll
      for (int fd = 0; fd < 4; ++fd) o[m][fd] *= corr;
      // pack P^T: r=0..3 are contiguous k -> one b64 write per fn
#pragma unroll
      for (int fn = 0; fn < 4; ++fn) {
        bf16x4 pk;
#pragma unroll
        for (int r = 0; r < 4; ++r) pk[r] = (bf16_t)s[m][fn][r];
        *(bf16x4*)&P_lds[w][m][l15][fn * 16 + lhi * 4] = pk;
      }
    }
    __builtin_amdgcn_wave_barrier();

    // O^T += V^T P^T
    __builtin_amdgcn_s_setprio(1);
#pragma unroll
    for (int m = 0; m < 2; ++m) {
      bf16x8 pf0 = *(const bf16x8*)&P_lds[w][m][l15][0 + lhi * 8];
      bf16x8 pf1 = *(const bf16x8*)&P_lds[w][m][l15][32 + lhi * 8];
#pragma unroll
      for (int fd = 0; fd < 4; ++fd) {
        o[m][fd] = __builtin_amdgcn_mfma_f32_16x16x32_bf16(vf[fd][0], pf0, o[m][fd], 0, 0, 0);
        o[m][fd] = __builtin_amdgcn_mfma_f32_16x16x32_bf16(vf[fd][1], pf1, o[m][fd], 0, 0, 0);
      }
    }
    __builtin_amdgcn_s_setprio(0);

#pragma unroll
    for (int fn = 0; fn < 4; ++fn)
#pragma unroll
      for (int kk = 0; kk < 2; ++kk)
        kc[fn][kk] = kn[fn][kk];
  }

  // epilogue: o col=q=l15, row=d=fd*16+lhi*4+r -> pack 4 contiguous d per store
  const int b = bh >> 4, h = bh & 15;
#pragma unroll
  for (int m = 0; m < 2; ++m) {
    const float inv = 1.0f / li[m];
    const size_t row = (size_t)b * 2048 + q0 + m * 16 + l15;
#pragma unroll
    for (int fd = 0; fd < 4; ++fd) {
      bf16x4 pk;
#pragma unroll
      for (int r = 0; r < 4; ++r) pk[r] = (bf16_t)(o[m][fd][r] * inv);
      *(bf16x4*)&O[row * 1024 + h * 64 + fd * 16 + lhi * 4] = pk;
    }
  }
}

// ---------------- launch ----------------
extern "C" void kernel_launch(void* const* d_in, const int* in_sizes, int n_in,
                              void* d_out, int out_size, void* d_ws, size_t ws_size,
                              hipStream_t stream) {
  const float* x  = (const float*)d_in[0];
  const float* wq = (const float*)d_in[1];
  const float* bq = (const float*)d_in[2];
  const float* wk = (const float*)d_in[3];
  const float* bk = (const float*)d_in[4];
  const float* wv = (const float*)d_in[5];
  const float* bv = (const float*)d_in[6];
  const float* wo = (const float*)d_in[7];
  const float* bo = (const float*)d_in[8];
  float* out = (float*)d_out;

  if (ws_size < ((size_t)48 << 20)) return;  // need 48MB scratch
  char* ws = (char*)d_ws;
  bf16_t* xb  = (bf16_t*)(ws);                    // 8MB x bf16 [4096][1024]; reused as O after proj
  bf16_t* wT  = (bf16_t*)(ws + ((size_t)8 << 20)); // 6MB wqkvT [3072][1024] + 2MB woT
  bf16_t* woT = wT + (size_t)3072 * 1024;
  bf16_t* Qb  = (bf16_t*)(ws + ((size_t)16 << 20)); // [2][16][2048][64] bf16
  bf16_t* Kb  = (bf16_t*)(ws + ((size_t)24 << 20));
  bf16_t* Vb  = (bf16_t*)(ws + ((size_t)32 << 20));
  bf16_t* Vt  = (bf16_t*)(ws + ((size_t)40 << 20)); // [2][16][64][2048]
  bf16_t* O   = xb;

  cast_x_k<<<4096, 256, 0, stream>>>(x, xb);
  transpose_w_k<<<dim3(16, 16, 4), 256, 0, stream>>>(wq, wk, wv, wo, wT, woT);
  gemm_k<0><<<dim3(24, 32), 256, 0, stream>>>(xb, wT, Qb, Kb, Vb, bq, bk, bv, nullptr, nullptr);
  transpose_v_k<<<dim3(32, 32), 256, 0, stream>>>(Vb, Vt);
  attn_k<<<512, 256, 0, stream>>>(Qb, Kb, Vt, O);
  gemm_k<1><<<dim3(8, 32), 256, 0, stream>>>(O, woT, nullptr, nullptr, nullptr,
                                             nullptr, nullptr, nullptr, out, bo);
}

// Round 4
// 197.603 us; speedup vs baseline: 1.3417x; 1.0018x over previous
//
#include <hip/hip_runtime.h>
#include <stdint.h>
#include <stddef.h>

// MHA forward, MI355X gfx950. B=2 S=2048 D=1024 H=16 hd=64.
// bf16 MFMA, fp32 accum, fp32 output.

typedef __bf16 bf16_t;
typedef __bf16 bf16x8 __attribute__((ext_vector_type(8)));
typedef __bf16 bf16x4 __attribute__((ext_vector_type(4)));
typedef __bf16 bf16x2 __attribute__((ext_vector_type(2)));
typedef float  f32x4  __attribute__((ext_vector_type(4)));
typedef float  f32x16 __attribute__((ext_vector_type(16)));
typedef uint32_t u32x4 __attribute__((ext_vector_type(4)));

static constexpr float kQScale = 0.18033688011112042f; // (1/sqrt(64)) * log2(e); softmax in base-2

__device__ __forceinline__ void gload_lds16(const bf16_t* g, bf16_t* l) {
  __builtin_amdgcn_global_load_lds((__attribute__((address_space(1))) void*)(void*)g,
                                   (__attribute__((address_space(3))) void*)l, 16, 0, 0);
}

// pack two f32 -> one u32 of 2 bf16 (compiler emits v_cvt_pk_bf16_f32)
__device__ __forceinline__ uint32_t pk_bf16(float lo, float hi) {
  bf16x2 v; v[0] = (bf16_t)lo; v[1] = (bf16_t)hi;
  return __builtin_bit_cast(uint32_t, v);
}

// ---------------- K1: cast x (f32) -> xb (bf16) ----------------
__global__ __launch_bounds__(256) void cast_x_k(const float* __restrict__ x, bf16_t* __restrict__ xb) {
  int i = blockIdx.x * 256 + threadIdx.x;
  float4 v = ((const float4*)x)[i];
  bf16x4 o;
  o[0] = (bf16_t)v.x; o[1] = (bf16_t)v.y; o[2] = (bf16_t)v.z; o[3] = (bf16_t)v.w;
  ((bf16x4*)xb)[i] = o;
}

// ---------------- K2: transpose+cast weights: wT[n][k] = w[k][n] ----------------
__global__ __launch_bounds__(256) void transpose_w_k(
    const float* __restrict__ wq, const float* __restrict__ wk,
    const float* __restrict__ wv, const float* __restrict__ wo,
    bf16_t* __restrict__ wqkvT, bf16_t* __restrict__ woT) {
  __shared__ float t[64][65];
  int z = blockIdx.z;
  const float* src = z == 0 ? wq : z == 1 ? wk : z == 2 ? wv : wo;
  bf16_t* dst = z < 3 ? wqkvT + (size_t)z * 1024 * 1024 : woT;
  int n0 = blockIdx.x * 64, k0 = blockIdx.y * 64;
  int c = threadIdx.x & 63, r4 = threadIdx.x >> 6;
#pragma unroll
  for (int i = 0; i < 16; ++i) {
    int r = r4 + i * 4;
    t[r][c] = src[(size_t)(k0 + r) * 1024 + (n0 + c)];
  }
  __syncthreads();
#pragma unroll
  for (int i = 0; i < 16; ++i) {
    int r = r4 + i * 4;
    dst[(size_t)(n0 + r) * 1024 + (k0 + c)] = (bf16_t)t[c][r];
  }
}

// ---------------- K3/K6: bf16 GEMM, m97 structure (128x128 tile, BK=32) ----------------
template <int EPI>
__global__ __launch_bounds__(256) void gemm_k(
    const bf16_t* __restrict__ A, const bf16_t* __restrict__ Bw,
    bf16_t* __restrict__ Qb, bf16_t* __restrict__ Kb, bf16_t* __restrict__ Vb,
    const float* __restrict__ bq, const float* __restrict__ bk, const float* __restrict__ bv,
    float* __restrict__ outF, const float* __restrict__ bo) {
  __shared__ alignas(16) bf16_t As[128 * 32];
  __shared__ alignas(16) bf16_t Bs[128 * 32];
  const int tid = threadIdx.x;
  const int lane = tid & 63;
  const int w = tid >> 6, wr = w >> 1, wc = w & 1;
  const int brow = blockIdx.y * 128, bcol = blockIdx.x * 128;
  const int l15 = lane & 15, ko = (lane >> 4) * 8;

  f32x4 acc[4][4] = {};
  const bf16_t* Ab = A + (size_t)brow * 1024;
  const bf16_t* Bb = Bw + (size_t)bcol * 1024;

  const int e0 = tid * 8;
  const int r0 = e0 >> 5, c0 = e0 & 31;

  for (int k0 = 0; k0 < 1024; k0 += 32) {
    gload_lds16(Ab + (size_t)r0 * 1024 + k0 + c0, &As[e0]);
    gload_lds16(Ab + (size_t)(r0 + 64) * 1024 + k0 + c0, &As[e0 + 2048]);
    gload_lds16(Bb + (size_t)r0 * 1024 + k0 + c0, &Bs[e0]);
    gload_lds16(Bb + (size_t)(r0 + 64) * 1024 + k0 + c0, &Bs[e0 + 2048]);
    __syncthreads();
    bf16x8 af[4], bfg[4];
#pragma unroll
    for (int i = 0; i < 4; ++i)
      af[i] = *(const bf16x8*)&As[(wr * 64 + i * 16 + l15) * 32 + ko];
#pragma unroll
    for (int i = 0; i < 4; ++i)
      bfg[i] = *(const bf16x8*)&Bs[(wc * 64 + i * 16 + l15) * 32 + ko];
#pragma unroll
    for (int i = 0; i < 4; ++i)
#pragma unroll
      for (int j = 0; j < 4; ++j)
        acc[i][j] = __builtin_amdgcn_mfma_f32_16x16x32_bf16(af[i], bfg[j], acc[i][j], 0, 0, 0);
    __syncthreads();
  }

#pragma unroll
  for (int i = 0; i < 4; ++i) {
    const int gm0 = brow + wr * 64 + i * 16 + ((lane >> 4) << 2);
#pragma unroll
    for (int j = 0; j < 4; ++j) {
      const int gn = bcol + wc * 64 + j * 16 + l15;
      if constexpr (EPI == 0) {
        const int mat = gn >> 10;
        const int col = gn & 1023;
        bf16_t* dst = mat == 0 ? Qb : (mat == 1 ? Kb : Vb);
        const float* bias = mat == 0 ? bq : (mat == 1 ? bk : bv);
        const float scl = mat == 0 ? kQScale : 1.0f;
        const float bsv = bias[col];
        const int h = col >> 6, dd = col & 63;
#pragma unroll
        for (int r = 0; r < 4; ++r) {
          const int m = gm0 + r;
          const int b = m >> 11, s = m & 2047;
          dst[((((size_t)b * 16 + h) * 2048 + s) * 64 + dd)] = (bf16_t)((acc[i][j][r] + bsv) * scl);
        }
      } else {
        const float bsv = bo[gn];
#pragma unroll
        for (int r = 0; r < 4; ++r)
          outF[(size_t)(gm0 + r) * 1024 + gn] = acc[i][j][r] + bsv;
      }
    }
  }
}

// ---------------- K4: transpose V [bh][s][64] -> Vt [bh][64][s] ----------------
__global__ __launch_bounds__(256) void transpose_v_k(const bf16_t* __restrict__ V, bf16_t* __restrict__ Vt) {
  __shared__ bf16_t t[64][65];
  int bh = blockIdx.y, s0 = blockIdx.x * 64;
  const bf16_t* src = V + (size_t)bh * 2048 * 64;
  bf16_t* dst = Vt + (size_t)bh * 64 * 2048;
  int c = threadIdx.x & 63, r4 = threadIdx.x >> 6;
#pragma unroll
  for (int i = 0; i < 16; ++i) {
    int r = r4 + i * 4;
    t[r][c] = src[(size_t)(s0 + r) * 64 + c];
  }
  __syncthreads();
#pragma unroll
  for (int i = 0; i < 16; ++i) {
    int d = r4 + i * 4;
    dst[(size_t)d * 2048 + s0 + c] = t[c][d];
  }
}

// ---------------- K5: flash attention, 32x32 MFMA, zero-LDS inner loop ----------------
// Q [bh][s][64] (pre-scaled by log2e/8), K [bh][s][64], Vt [bh][64][s], all bf16.
// 4 independent waves/block; wave owns 32 q-rows. KV tile = 64 (2 subtiles of 32).
// S^T = mfma(K,Q) 32x32x16: C-layout col=q=lane&31, row=key=(reg&3)+8*(reg>>2)+4*hi.
// Softmax fully in-lane + one shfl_xor(32) per reduce. P^T B-fragments built with
// cvt_pk + shfl_xor(32) + cndmask (guaranteed-semantics only; assumed k-map is
// identical on V^T side so any true-map permutation cancels). O^T = mfma(V^T, P^T).
__global__ __launch_bounds__(256, 2) void attn_k(
    const bf16_t* __restrict__ Qb, const bf16_t* __restrict__ Kb,
    const bf16_t* __restrict__ Vt, bf16_t* __restrict__ O) {
  const int tid = threadIdx.x, lane = tid & 63, w = tid >> 6;
  const int l31 = lane & 31, hi = lane >> 5;
  // bijective XCD-chunked swizzle: 512 blocks, 64 consecutive per XCD -> 4 heads/XCD L2
  const int work = (blockIdx.x & 7) * 64 + (blockIdx.x >> 3);
  const int bh = work >> 4;
  const int q0 = (work & 15) * 128 + w * 32;

  const bf16_t* Qp = Qb + ((size_t)bh * 2048 + q0) * 64;
  const bf16_t* Kp = Kb + (size_t)bh * 2048 * 64;
  const bf16_t* Vp = Vt + (size_t)bh * 64 * 2048;

  // Q B-operand: col=q=l31, contraction d = ds*16 + hi*8 + j (assumed map; cancels vs K)
  bf16x8 qf[4];
#pragma unroll
  for (int ds = 0; ds < 4; ++ds)
    qf[ds] = *(const bf16x8*)&Qp[(size_t)l31 * 64 + ds * 16 + hi * 8];

  f32x16 o0 = {}, o1 = {};
  float mx = -1e30f, li = 0.0f;

  bf16x8 kc[2][4], kn[2][4];
#pragma unroll
  for (int st = 0; st < 2; ++st)
#pragma unroll
    for (int ds = 0; ds < 4; ++ds)
      kc[st][ds] = *(const bf16x8*)&Kp[(size_t)(st * 32 + l31) * 64 + ds * 16 + hi * 8];

  auto body = [&](bf16x8 (&kcur)[2][4], bf16x8 (&knxt)[2][4], int kv0) {
    const int nxt = (kv0 + 64 < 2048) ? kv0 + 64 : 0;  // wrap keeps addr valid; data unused on last iter
    // prefetch V(t) and K(t+1)
    bf16x8 vf[2][4];
#pragma unroll
    for (int dt = 0; dt < 2; ++dt)
#pragma unroll
      for (int ks = 0; ks < 4; ++ks)
        vf[dt][ks] = *(const bf16x8*)&Vp[(size_t)(dt * 32 + l31) * 2048 + kv0 + ks * 16 + hi * 8];
#pragma unroll
    for (int st = 0; st < 2; ++st)
#pragma unroll
      for (int ds = 0; ds < 4; ++ds)
        knxt[st][ds] = *(const bf16x8*)&Kp[(size_t)(nxt + st * 32 + l31) * 64 + ds * 16 + hi * 8];

    // S^T = K Q^T (Q pre-scaled). Subtile st covers keys kv0+32st .. +31.
    f32x16 s0 = {}, s1 = {};
    __builtin_amdgcn_s_setprio(1);
#pragma unroll
    for (int ds = 0; ds < 4; ++ds)
      s0 = __builtin_amdgcn_mfma_f32_32x32x16_bf16(kcur[0][ds], qf[ds], s0, 0, 0, 0);
#pragma unroll
    for (int ds = 0; ds < 4; ++ds)
      s1 = __builtin_amdgcn_mfma_f32_32x32x16_bf16(kcur[1][ds], qf[ds], s1, 0, 0, 0);
    __builtin_amdgcn_s_setprio(0);

    // online softmax: lane (q=l31,hi) owns keys 8g+4hi+rr (16 per subtile)
    float t = fmaxf(s0[0], s0[1]);
#pragma unroll
    for (int r = 2; r < 16; ++r) t = fmaxf(t, s0[r]);
#pragma unroll
    for (int r = 0; r < 16; ++r) t = fmaxf(t, s1[r]);
    t = fmaxf(t, __shfl_xor(t, 32));
    const float mn = fmaxf(mx, t);
    const float corr = exp2f(mx - mn);
    mx = mn;
    float rs = 0.0f;
#pragma unroll
    for (int r = 0; r < 16; ++r) { const float p = exp2f(s0[r] - mn); s0[r] = p; rs += p; }
#pragma unroll
    for (int r = 0; r < 16; ++r) { const float p = exp2f(s1[r] - mn); s1[r] = p; rs += p; }
    rs += __shfl_xor(rs, 32);
    li = li * corr + rs;
#pragma unroll
    for (int r = 0; r < 16; ++r) { o0[r] *= corr; o1[r] *= corr; }

    // pack P -> bf16 words: word (g,c) holds keys(local32) (8g+4hi+2c, 8g+4hi+2c+1)
    uint32_t pw0[8], pw1[8];
#pragma unroll
    for (int g = 0; g < 4; ++g) {
      pw0[g * 2 + 0] = pk_bf16(s0[4 * g + 0], s0[4 * g + 1]);
      pw0[g * 2 + 1] = pk_bf16(s0[4 * g + 2], s0[4 * g + 3]);
      pw1[g * 2 + 0] = pk_bf16(s1[4 * g + 0], s1[4 * g + 1]);
      pw1[g * 2 + 1] = pk_bf16(s1[4 * g + 2], s1[4 * g + 3]);
    }

    // PV: O^T += V^T P^T. B-frag for 16-key slice (st,ks): element (hi,j) must hold
    // local16 key 8hi+j. hi0 needs {A@hi0 | A@hi1}, hi1 needs {B@hi0 | B@hi1}
    // where A=word(g=2ks,c), B=word(g=2ks+1,c). Exchange via shfl_xor(32)+select.
#pragma unroll
    for (int st = 0; st < 2; ++st) {
      uint32_t (&pw)[8] = st ? pw1 : pw0;
#pragma unroll
      for (int ks = 0; ks < 2; ++ks) {
        const uint32_t A0 = pw[(2 * ks) * 2 + 0], A1 = pw[(2 * ks) * 2 + 1];
        const uint32_t B0 = pw[(2 * ks + 1) * 2 + 0], B1 = pw[(2 * ks + 1) * 2 + 1];
        const uint32_t Z0 = hi ? A0 : B0;   // word the other half needs from this lane
        const uint32_t Z1 = hi ? A1 : B1;
        const uint32_t sZ0 = (uint32_t)__shfl_xor((int)Z0, 32);
        const uint32_t sZ1 = (uint32_t)__shfl_xor((int)Z1, 32);
        u32x4 fw;
        fw[0] = hi ? sZ0 : A0;   // j=0,1
        fw[1] = hi ? sZ1 : A1;   // j=2,3
        fw[2] = hi ? B0 : sZ0;   // j=4,5
        fw[3] = hi ? B1 : sZ1;   // j=6,7
        const bf16x8 pf = __builtin_bit_cast(bf16x8, fw);
        __builtin_amdgcn_s_setprio(1);
        o0 = __builtin_amdgcn_mfma_f32_32x32x16_bf16(vf[0][st * 2 + ks], pf, o0, 0, 0, 0);
        o1 = __builtin_amdgcn_mfma_f32_32x32x16_bf16(vf[1][st * 2 + ks], pf, o1, 0, 0, 0);
        __builtin_amdgcn_s_setprio(0);
      }
    }
  };

  for (int kv0 = 0; kv0 < 2048; kv0 += 128) {
    body(kc, kn, kv0);
    body(kn, kc, kv0 + 64);
  }

  // epilogue: O^T C-layout: col=q=l31, row d = 32dt + 8g + 4hi + r
  const int b = bh >> 4, h = bh & 15;
  const float inv = 1.0f / li;
  const size_t row = (size_t)b * 2048 + q0 + l31;
#pragma unroll
  for (int g = 0; g < 4; ++g) {
    bf16x4 p0, p1;
#pragma unroll
    for (int r = 0; r < 4; ++r) {
      p0[r] = (bf16_t)(o0[4 * g + r] * inv);
      p1[r] = (bf16_t)(o1[4 * g + r] * inv);
    }
    *(bf16x4*)&O[row * 1024 + h * 64 + 0  + g * 8 + hi * 4] = p0;
    *(bf16x4*)&O[row * 1024 + h * 64 + 32 + g * 8 + hi * 4] = p1;
  }
}

// ---------------- launch ----------------
extern "C" void kernel_launch(void* const* d_in, const int* in_sizes, int n_in,
                              void* d_out, int out_size, void* d_ws, size_t ws_size,
                              hipStream_t stream) {
  const float* x  = (const float*)d_in[0];
  const float* wq = (const float*)d_in[1];
  const float* bq = (const float*)d_in[2];
  const float* wk = (const float*)d_in[3];
  const float* bk = (const float*)d_in[4];
  const float* wv = (const float*)d_in[5];
  const float* bv = (const float*)d_in[6];
  const float* wo = (const float*)d_in[7];
  const float* bo = (const float*)d_in[8];
  float* out = (float*)d_out;

  if (ws_size < ((size_t)48 << 20)) return;  // need 48MB scratch
  char* ws = (char*)d_ws;
  bf16_t* xb  = (bf16_t*)(ws);                     // 8MB x bf16 [4096][1024]; reused as O after proj
  bf16_t* wT  = (bf16_t*)(ws + ((size_t)8 << 20)); // 6MB wqkvT [3072][1024] + 2MB woT
  bf16_t* woT = wT + (size_t)3072 * 1024;
  bf16_t* Qb  = (bf16_t*)(ws + ((size_t)16 << 20)); // [2][16][2048][64] bf16
  bf16_t* Kb  = (bf16_t*)(ws + ((size_t)24 << 20));
  bf16_t* Vb  = (bf16_t*)(ws + ((size_t)32 << 20));
  bf16_t* Vt  = (bf16_t*)(ws + ((size_t)40 << 20)); // [2][16][64][2048]
  bf16_t* O   = xb;

  cast_x_k<<<4096, 256, 0, stream>>>(x, xb);
  transpose_w_k<<<dim3(16, 16, 4), 256, 0, stream>>>(wq, wk, wv, wo, wT, woT);
  gemm_k<0><<<dim3(24, 32), 256, 0, stream>>>(xb, wT, Qb, Kb, Vb, bq, bk, bv, nullptr, nullptr);
  transpose_v_k<<<dim3(32, 32), 256, 0, stream>>>(Vb, Vt);
  attn_k<<<512, 256, 0, stream>>>(Qb, Kb, Vt, O);
  gemm_k<1><<<dim3(8, 32), 256, 0, stream>>>(O, woT, nullptr, nullptr, nullptr,
                                             nullptr, nullptr, nullptr, out, bo);
}